// Round 1
// baseline (332.644 us; speedup 1.0000x reference)
//
#include <hip/hip_runtime.h>

// Problem constants (from reference)
#define BB   8
#define CC   256
#define HH   64
#define WW   64
#define CR   64     // reduced channels (C/4)
#define NG   32     // groups
#define GC   8      // group_channels
#define KK   25     // 5x5 taps
#define HW   (HH*WW)

// ---------------------------------------------------------------------------
// Prep kernel: fold BN into transposed conv1 weights.
//   w1tf[c*64 + o] = w1[o*256 + c] * scale[o]
//   b1f[o]         = (b1[o] - mean[o]) * scale[o] + beta[o]
// where scale[o] = gamma[o] * rsqrt(var[o] + eps).
// Then y = clip(dot(x, w1tf_col) + b1f, 0, 6) reproduces conv1+BN+ReLU6.
// ---------------------------------------------------------------------------
__global__ __launch_bounds__(256) void prep_kernel(
    const float* __restrict__ w1, const float* __restrict__ b1,
    const float* __restrict__ gamma, const float* __restrict__ beta,
    const float* __restrict__ mean, const float* __restrict__ var,
    float* __restrict__ w1tf, float* __restrict__ b1f)
{
    int idx = blockIdx.x * 256 + threadIdx.x;   // 0..16383
    int o = idx & 63;
    int c = idx >> 6;
    float scale = gamma[o] * rsqrtf(var[o] + 1e-5f);
    w1tf[idx] = w1[o * CC + c] * scale;
    if (idx < CR) {
        b1f[idx] = (b1[idx] - mean[idx]) * scale + beta[idx];  // o == idx here
    }
}

// ---------------------------------------------------------------------------
// Fused involution kernel. One block per (b, h): 256 threads = 4 waves.
// Phase 1: stage x[b, :, h, :] -> lds_x[256][64]            (64 KB)
// Phase 2: conv1+BN+ReLU6 -> lds_y[64][64]; wave wv does y-rows [wv*16,wv*16+16)
//          lane = pixel w. LDS reads lane-stride-1 (conflict-free), w1tf via
//          wave-uniform s_loads.
// Phase 3: lane = pixel w; wave wv handles groups [wv*8, wv*8+8).
//          y column in 64 VGPRs; per (g,t): kern = b2 + dot(w2_row[64], y)
//          (w2 row is wave-uniform -> s_load), then 8 channel taps from
//          global (L1/L2-cached, 25x reuse) accumulated into 64 out regs.
//          Padding: out-of-row-h -> uniform skip; out-of-col -> kern zeroed
//          per lane, address clamped (never OOB).
// ---------------------------------------------------------------------------
__global__ __launch_bounds__(256, 2) void invol_kernel(
    const float* __restrict__ x, const float* __restrict__ w1tf,
    const float* __restrict__ b1f, const float* __restrict__ w2,
    const float* __restrict__ b2, float* __restrict__ out)
{
    __shared__ float lds_x[CC * WW];   // [c][w] 64 KB
    __shared__ float lds_y[CR * WW];   // [r][w] 16 KB

    const int tid  = threadIdx.x;
    const int h    = blockIdx.x;
    const int b    = blockIdx.y;
    const int lane = tid & 63;
    const int wv   = __builtin_amdgcn_readfirstlane(tid >> 6);  // force SGPR

    // ---- Phase 1: stage x row (all 256 channels, 64 cols) ----
    #pragma unroll
    for (int k = 0; k < 16; ++k) {
        int f  = tid + k * 256;     // float4 index 0..4095
        int c  = f >> 4;
        int w4 = f & 15;
        float4 v = *(const float4*)(x + ((b * CC + c) * HH + h) * WW + w4 * 4);
        *(float4*)(&lds_x[c * WW + w4 * 4]) = v;
    }
    __syncthreads();

    // ---- Phase 2: conv1 + BN + ReLU6 -> lds_y ----
    {
        float acc[16];
        #pragma unroll
        for (int i = 0; i < 16; ++i) acc[i] = 0.0f;
        const int ob = wv * 16;     // uniform
        #pragma unroll 4
        for (int c = 0; c < CC; ++c) {
            float xv = lds_x[c * WW + lane];
            const float* wr = w1tf + c * CR + ob;   // uniform address
            #pragma unroll
            for (int i = 0; i < 16; ++i) acc[i] += wr[i] * xv;
        }
        #pragma unroll
        for (int i = 0; i < 16; ++i) {
            float v = acc[i] + b1f[ob + i];
            v = fminf(fmaxf(v, 0.0f), 6.0f);
            lds_y[(ob + i) * WW + lane] = v;
        }
    }
    __syncthreads();

    // ---- Phase 3: conv2 (per-pixel kernels) + involution accumulate ----
    float yreg[CR];
    #pragma unroll
    for (int r = 0; r < CR; ++r) yreg[r] = lds_y[r * WW + lane];

    float oacc[64];
    #pragma unroll
    for (int i = 0; i < 64; ++i) oacc[i] = 0.0f;

    #pragma unroll
    for (int gl = 0; gl < 8; ++gl) {
        const int g = wv * 8 + gl;                  // uniform
        for (int t = 0; t < KK; ++t) {
            const float* w2r = w2 + (g * KK + t) * CR;   // uniform -> s_load
            float kern = b2[g * KK + t];
            #pragma unroll
            for (int r = 0; r < CR; ++r) kern += w2r[r] * yreg[r];

            int di = t / 5;
            int dj = t - di * 5;
            int hh = h + di - 2;                    // uniform
            if (hh >= 0 && hh < HH) {
                int ww   = lane + dj - 2;
                float km = (ww >= 0 && ww < WW) ? kern : 0.0f;
                int wwc  = min(max(ww, 0), WW - 1); // clamp: address stays in-bounds
                const float* xt = x + ((b * CC + g * GC) * HH + hh) * WW + wwc;
                #pragma unroll
                for (int j = 0; j < GC; ++j)
                    oacc[gl * GC + j] += km * xt[j * HW];
            }
        }
    }

    // ---- Store: wave wv owns channels [wv*64, wv*64+64) ----
    float* orow = out + ((b * CC + wv * 64) * HH + h) * WW + lane;
    #pragma unroll
    for (int i = 0; i < 64; ++i) orow[i * HW] = oacc[i];
}

extern "C" void kernel_launch(void* const* d_in, const int* in_sizes, int n_in,
                              void* d_out, int out_size, void* d_ws, size_t ws_size,
                              hipStream_t stream) {
    const float* x     = (const float*)d_in[0];
    const float* w1    = (const float*)d_in[1];
    const float* b1    = (const float*)d_in[2];
    const float* gamma = (const float*)d_in[3];
    const float* beta  = (const float*)d_in[4];
    const float* mean  = (const float*)d_in[5];
    const float* var   = (const float*)d_in[6];
    const float* w2    = (const float*)d_in[7];
    const float* b2    = (const float*)d_in[8];
    float* out = (float*)d_out;

    float* w1tf = (float*)d_ws;              // 16384 floats
    float* b1f  = w1tf + CC * CR;            // 64 floats

    prep_kernel<<<64, 256, 0, stream>>>(w1, b1, gamma, beta, mean, var, w1tf, b1f);
    invol_kernel<<<dim3(HH, BB), 256, 0, stream>>>(x, w1tf, b1f, w2, b2, out);
}

// Round 2
// 290.256 us; speedup vs baseline: 1.1460x; 1.1460x over previous
//
#include <hip/hip_runtime.h>

// Problem constants (from reference)
#define BB   8
#define CC   256
#define HH   64
#define WW   64
#define CR   64     // reduced channels (C/4)
#define NG   32     // groups
#define GC   8      // group_channels
#define KK   25     // 5x5 taps
#define HW   (HH*WW)

// ---------------------------------------------------------------------------
// Prep kernel: fold BN into transposed conv1 weights.
//   w1tf[c*64 + o] = w1[o*256 + c] * scale[o]
//   b1f[o]         = (b1[o] - mean[o]) * scale[o] + beta[o]
// ---------------------------------------------------------------------------
__global__ __launch_bounds__(256) void prep_kernel(
    const float* __restrict__ w1, const float* __restrict__ b1,
    const float* __restrict__ gamma, const float* __restrict__ beta,
    const float* __restrict__ mean, const float* __restrict__ var,
    float* __restrict__ w1tf, float* __restrict__ b1f)
{
    int idx = blockIdx.x * 256 + threadIdx.x;   // 0..16383
    int o = idx & 63;
    int c = idx >> 6;
    float scale = gamma[o] * rsqrtf(var[o] + 1e-5f);
    w1tf[idx] = w1[o * CC + c] * scale;
    if (idx < CR) {
        b1f[idx] = (b1[idx] - mean[idx]) * scale + beta[idx];  // o == idx
    }
}

// ---------------------------------------------------------------------------
// Kernel A: conv1 + BN + ReLU6 -> y[b][r][h][w] in workspace.
// Block = (h, b), 256 threads = 4 waves; wave wv computes y rows
// [wv*16, wv*16+16) for all 64 pixels of the row. lane = pixel w.
// x loads are lane-coalesced (256B/wave), shared across the 4 waves via L1.
// acc[16] gives 16 independent FMA chains per load; unroll 8 keeps 8 loads
// in flight.
// ---------------------------------------------------------------------------
__global__ __launch_bounds__(256) void conv1_kernel(
    const float* __restrict__ x, const float* __restrict__ w1tf,
    const float* __restrict__ b1f, float* __restrict__ y)
{
    const int tid  = threadIdx.x;
    const int h    = blockIdx.x;
    const int b    = blockIdx.y;
    const int lane = tid & 63;
    const int wv   = __builtin_amdgcn_readfirstlane(tid >> 6);
    const int ob   = wv * 16;    // uniform

    float acc[16];
    #pragma unroll
    for (int i = 0; i < 16; ++i) acc[i] = 0.0f;

    const float* xcol = x + (b * CC * HH + h) * WW + lane;
    #pragma unroll 8
    for (int c = 0; c < CC; ++c) {
        float xv = xcol[c * HW];
        const float* wr = w1tf + c * CR + ob;   // uniform -> s_load
        #pragma unroll
        for (int i = 0; i < 16; ++i) acc[i] = fmaf(wr[i], xv, acc[i]);
    }

    float* ycol = y + (b * CR * HH + h) * WW + lane;
    #pragma unroll
    for (int i = 0; i < 16; ++i) {
        float v = acc[i] + b1f[ob + i];
        v = fminf(fmaxf(v, 0.0f), 6.0f);
        ycol[(ob + i) * HW] = v;
    }
}

// ---------------------------------------------------------------------------
// Kernel B: conv2 (per-pixel kernels) + involution accumulate.
// Grid = (h=64, b=8, gq=2) = 1024 blocks -> 4 blocks/CU. No LDS.
// 256 threads = 4 waves; wave wv handles groups gq*16 + wv*4 .. +4.
// lane = pixel w. y column (64 values) held in VGPRs, read once per block
// (L1/L2-served, shared across waves/blocks).
// Per group, per kernel row di: 5 independent 64-FMA dot products (kern5)
// using wave-uniform s_loads of w2 rows, then 40 independent tap
// loads + FMAs. Out-of-row-h rows skipped uniformly; out-of-col lanes get
// kern zeroed with clamped (in-bounds) addresses.
// ---------------------------------------------------------------------------
__global__ __launch_bounds__(256) void invol_kernel(
    const float* __restrict__ x, const float* __restrict__ y,
    const float* __restrict__ w2, const float* __restrict__ b2,
    float* __restrict__ out)
{
    const int tid  = threadIdx.x;
    const int h    = blockIdx.x;
    const int b    = blockIdx.y;
    const int gq   = blockIdx.z;   // 0..1
    const int lane = tid & 63;
    const int wv   = __builtin_amdgcn_readfirstlane(tid >> 6);

    // y column for this pixel: 64 regs
    float yreg[CR];
    const float* ycol = y + (b * CR * HH + h) * WW + lane;
    #pragma unroll
    for (int r = 0; r < CR; ++r) yreg[r] = ycol[r * HW];

    #pragma unroll 1
    for (int gl = 0; gl < 4; ++gl) {
        const int g = gq * 16 + wv * 4 + gl;       // uniform
        const float* w2g = w2 + g * (KK * CR);     // uniform base
        const float* b2g = b2 + g * KK;

        float oacc[GC];
        #pragma unroll
        for (int j = 0; j < GC; ++j) oacc[j] = 0.0f;

        #pragma unroll
        for (int di = 0; di < 5; ++di) {
            const int hh = h + di - 2;             // uniform
            if (hh >= 0 && hh < HH) {
                // 5 independent dot products for this kernel row
                float kern5[5];
                #pragma unroll
                for (int dj = 0; dj < 5; ++dj) {
                    const int t = di * 5 + dj;
                    const float* w2r = w2g + t * CR;   // uniform -> s_load
                    float k = b2g[t];
                    #pragma unroll
                    for (int r = 0; r < CR; ++r)
                        k = fmaf(w2r[r], yreg[r], k);
                    kern5[dj] = k;
                }
                // 5 taps x 8 channels of independent loads + FMAs
                const float* xrow = x + ((b * CC + g * GC) * HH + hh) * WW;
                #pragma unroll
                for (int dj = 0; dj < 5; ++dj) {
                    int ww   = lane + dj - 2;
                    float km = (ww >= 0 && ww < WW) ? kern5[dj] : 0.0f;
                    int wwc  = min(max(ww, 0), WW - 1);   // in-bounds clamp
                    const float* xt = xrow + wwc;
                    #pragma unroll
                    for (int j = 0; j < GC; ++j)
                        oacc[j] = fmaf(km, xt[j * HW], oacc[j]);
                }
            }
        }

        float* orow = out + ((b * CC + g * GC) * HH + h) * WW + lane;
        #pragma unroll
        for (int j = 0; j < GC; ++j) orow[j * HW] = oacc[j];
    }
}

extern "C" void kernel_launch(void* const* d_in, const int* in_sizes, int n_in,
                              void* d_out, int out_size, void* d_ws, size_t ws_size,
                              hipStream_t stream) {
    const float* x     = (const float*)d_in[0];
    const float* w1    = (const float*)d_in[1];
    const float* b1    = (const float*)d_in[2];
    const float* gamma = (const float*)d_in[3];
    const float* beta  = (const float*)d_in[4];
    const float* mean  = (const float*)d_in[5];
    const float* var   = (const float*)d_in[6];
    const float* w2    = (const float*)d_in[7];
    const float* b2    = (const float*)d_in[8];
    float* out = (float*)d_out;

    float* w1tf = (float*)d_ws;              // 16384 floats
    float* b1f  = w1tf + CC * CR;            // 64 floats
    float* yws  = b1f + CR;                  // 8*64*64*64 = 2,097,152 floats

    prep_kernel<<<64, 256, 0, stream>>>(w1, b1, gamma, beta, mean, var, w1tf, b1f);
    conv1_kernel<<<dim3(HH, BB), 256, 0, stream>>>(x, w1tf, b1f, yws);
    invol_kernel<<<dim3(HH, BB, 2), 256, 0, stream>>>(x, yws, w2, b2, out);
}

// Round 3
// 196.891 us; speedup vs baseline: 1.6895x; 1.4742x over previous
//
#include <hip/hip_runtime.h>

// Problem constants
#define BB   8
#define CC   256
#define HH   64
#define WW   64
#define CR   64     // reduced channels
#define NG   32     // groups
#define GC   8      // group_channels
#define KK   25     // 5x5 taps
#define HW   (HH*WW)

typedef __attribute__((ext_vector_type(8))) short short8;   // 8 bf16 = 4 VGPRs
typedef __attribute__((ext_vector_type(4))) float f32x4;    // MFMA C/D

__device__ __forceinline__ unsigned short f2bf(float f) {
    unsigned u = __builtin_bit_cast(unsigned, f);
    u += 0x7FFFu + ((u >> 16) & 1u);          // round-to-nearest-even
    return (unsigned short)(u >> 16);
}

// ---------------------------------------------------------------------------
// prep1: fold BN into transposed conv1 weights (fp32).
// ---------------------------------------------------------------------------
__global__ __launch_bounds__(256) void prep1_kernel(
    const float* __restrict__ w1, const float* __restrict__ b1,
    const float* __restrict__ gamma, const float* __restrict__ beta,
    const float* __restrict__ mean, const float* __restrict__ var,
    float* __restrict__ w1tf, float* __restrict__ b1f)
{
    int idx = blockIdx.x * 256 + threadIdx.x;   // 0..16383
    int o = idx & 63;
    int c = idx >> 6;
    float scale = gamma[o] * rsqrtf(var[o] + 1e-5f);
    w1tf[idx] = w1[o * CC + c] * scale;
    if (idx < CR) b1f[idx] = (b1[idx] - mean[idx]) * scale + beta[idx];
}

// ---------------------------------------------------------------------------
// prep2: pack w2 into bf16 B-fragment layout for mfma_f32_16x16x32_bf16.
// B[k][n] = w2[g*25 + n_local][k]; lane l holds n = l&15, k = ki*32+(l>>4)*8+j.
// w2p[((g*2+nt)*2+ki)*512 + l*8 + j]; padded cols (n_local>=25) = 0.
// ---------------------------------------------------------------------------
__global__ __launch_bounds__(256) void prep2_kernel(
    const float* __restrict__ w2, unsigned short* __restrict__ w2p)
{
    int idx = blockIdx.x * 256 + threadIdx.x;   // 0..65535
    int j  = idx & 7;
    int l  = (idx >> 3) & 63;
    int ki = (idx >> 9) & 1;
    int nt = (idx >> 10) & 1;
    int g  = idx >> 11;
    int nl = nt * 16 + (l & 15);
    int k  = ki * 32 + (l >> 4) * 8 + j;
    float v = (nl < KK) ? w2[(g * KK + nl) * CR + k] : 0.0f;
    w2p[idx] = f2bf(v);
}

// ---------------------------------------------------------------------------
// conv1: y = ReLU6(BN(x . w1)) -> bf16, layout ybf[b][h][w][r] (A-frag friendly).
// lane = output channel r (64 == wave size): w1tf loads are per-lane coalesced
// VMEM (reused across px, L1-served); x values are wave-uniform -> s_load of
// 32 B per channel (fits SGPR budget, deep pipelining via unroll).
// Grid (2, H, B) = 1024 blocks; wave wv covers 8 pixels (acc[8]).
// ---------------------------------------------------------------------------
__global__ __launch_bounds__(256) void conv1_kernel(
    const float* __restrict__ x, const float* __restrict__ w1tf,
    const float* __restrict__ b1f, unsigned short* __restrict__ ybf)
{
    const int tid  = threadIdx.x;
    const int pq   = blockIdx.x;          // 0..1
    const int h    = blockIdx.y;
    const int b    = blockIdx.z;
    const int lane = tid & 63;
    const int wv   = tid >> 6;
    const int px0  = pq * 32 + wv * 8;

    float acc[8];
    #pragma unroll
    for (int p = 0; p < 8; ++p) acc[p] = 0.0f;

    const float* xb = x + (size_t)b * CC * HW + h * WW + px0;
    #pragma unroll 8
    for (int c = 0; c < CC; ++c) {
        float w = w1tf[c * CR + lane];        // per-lane coalesced
        const float* xr = xb + c * HW;        // wave-uniform -> s_load
        #pragma unroll
        for (int p = 0; p < 8; ++p) acc[p] = fmaf(w, xr[p], acc[p]);
    }

    float bv = b1f[lane];
    unsigned short* yb = ybf + ((size_t)(b * HH + h) * WW + px0) * CR + lane;
    #pragma unroll
    for (int p = 0; p < 8; ++p) {
        float v = fminf(fmaxf(acc[p] + bv, 0.0f), 6.0f);
        yb[p * CR] = f2bf(v);
    }
}

// ---------------------------------------------------------------------------
// invol: per-pixel kernels via MFMA + involution accumulate.
// Grid (H, B, 2) = 1024 blocks, 4 waves; wave wv: 4 groups of half gq.
// A-frags (y row, 64px x 64k bf16) loaded once per wave from ybf.
// Per group: 16 MFMA (4 mt x 2 nt x 2 ki chain) with b2 folded into C init;
// C frags -> per-wave LDS [n][px] (stride 65); involution reads kern[t][lane]
// (2-way, free) and accumulates 25 taps x 8 channels with zero-VALU
// addressing (uniform channel base + hoisted clamped column offset).
// ---------------------------------------------------------------------------
__global__ __launch_bounds__(256, 4) void invol_kernel(
    const float* __restrict__ x, const unsigned short* __restrict__ ybf,
    const unsigned short* __restrict__ w2p, const float* __restrict__ b2,
    float* __restrict__ out)
{
    __shared__ float klds[4][32 * 65];    // per-wave kern tiles, 33,280 B

    const int tid  = threadIdx.x;
    const int h    = blockIdx.x;
    const int b    = blockIdx.y;
    const int gq   = blockIdx.z;          // 0..1
    const int lane = tid & 63;
    const int wv   = __builtin_amdgcn_readfirstlane(tid >> 6);
    float* kw = klds[wv];

    const int l15 = lane & 15;
    const int q   = lane >> 4;

    // ---- A fragments: y[px = mt*16+l15][k = ki*32 + q*8 + j] ----
    short8 afr[4][2];
    const unsigned short* yb = ybf + (size_t)(b * HH + h) * WW * CR;
    #pragma unroll
    for (int mt = 0; mt < 4; ++mt)
        #pragma unroll
        for (int ki = 0; ki < 2; ++ki)
            afr[mt][ki] = *(const short8*)(yb + (mt * 16 + l15) * CR + ki * 32 + q * 8);

    // ---- hoisted clamped tap-column offsets ----
    int  wwc[5];
    bool val[5];
    #pragma unroll
    for (int dj = 0; dj < 5; ++dj) {
        int ww  = lane + dj - 2;
        val[dj] = (ww >= 0) && (ww < WW);
        wwc[dj] = min(max(ww, 0), WW - 1);
    }

    const short8* w2p8 = (const short8*)w2p;

    #pragma unroll 1
    for (int gl = 0; gl < 4; ++gl) {
        const int g = gq * 16 + wv * 4 + gl;   // uniform

        // ---- C init = b2 broadcast (col n = nt*16 + l15) ----
        f32x4 cfr[4][2];
        #pragma unroll
        for (int nt = 0; nt < 2; ++nt) {
            int nl = nt * 16 + l15;
            float vb = b2[g * KK + min(nl, KK - 1)];
            vb = (nl < KK) ? vb : 0.0f;
            #pragma unroll
            for (int mt = 0; mt < 4; ++mt)
                cfr[mt][nt] = (f32x4){vb, vb, vb, vb};
        }

        // ---- MFMA: kern[px][n] = sum_k y[px][k] * w2[n][k] + b2 ----
        #pragma unroll
        for (int nt = 0; nt < 2; ++nt) {
            short8 bf0 = w2p8[((g * 2 + nt) * 2 + 0) * 64 + lane];
            short8 bf1 = w2p8[((g * 2 + nt) * 2 + 1) * 64 + lane];
            #pragma unroll
            for (int mt = 0; mt < 4; ++mt) {
                cfr[mt][nt] = __builtin_amdgcn_mfma_f32_16x16x32_bf16(
                    afr[mt][0], bf0, cfr[mt][nt], 0, 0, 0);
                cfr[mt][nt] = __builtin_amdgcn_mfma_f32_16x16x32_bf16(
                    afr[mt][1], bf1, cfr[mt][nt], 0, 0, 0);
            }
        }

        // ---- C -> LDS: kern_lds[n][px], row stride 65 ----
        #pragma unroll
        for (int mt = 0; mt < 4; ++mt)
            #pragma unroll
            for (int nt = 0; nt < 2; ++nt) {
                int n  = nt * 16 + l15;
                int px = mt * 16 + q * 4;
                #pragma unroll
                for (int r = 0; r < 4; ++r)
                    kw[n * 65 + px + r] = cfr[mt][nt][r];
            }

        // ---- involution: out[ch][lane] += kern[t][lane] * x_tap ----
        float oacc[GC];
        #pragma unroll
        for (int j = 0; j < GC; ++j) oacc[j] = 0.0f;

        const float* xg = x + (size_t)(b * CC + g * GC) * HW;
        #pragma unroll
        for (int di = 0; di < 5; ++di) {
            int hh = h + di - 2;                 // uniform
            if (hh >= 0 && hh < HH) {
                float ks[5];
                #pragma unroll
                for (int dj = 0; dj < 5; ++dj) {
                    float kv = kw[(di * 5 + dj) * 65 + lane];   // 2-way, free
                    ks[dj] = val[dj] ? kv : 0.0f;
                }
                #pragma unroll
                for (int j = 0; j < GC; ++j) {
                    const float* xc = xg + (j * HH + hh) * WW;  // uniform base
                    #pragma unroll
                    for (int dj = 0; dj < 5; ++dj)
                        oacc[j] = fmaf(ks[dj], xc[wwc[dj]], oacc[j]);
                }
            }
        }

        float* oc = out + ((size_t)(b * CC + g * GC) * HH + h) * WW + lane;
        #pragma unroll
        for (int j = 0; j < GC; ++j) oc[j * HW] = oacc[j];
    }
}

extern "C" void kernel_launch(void* const* d_in, const int* in_sizes, int n_in,
                              void* d_out, int out_size, void* d_ws, size_t ws_size,
                              hipStream_t stream) {
    const float* x     = (const float*)d_in[0];
    const float* w1    = (const float*)d_in[1];
    const float* b1    = (const float*)d_in[2];
    const float* gamma = (const float*)d_in[3];
    const float* beta  = (const float*)d_in[4];
    const float* mean  = (const float*)d_in[5];
    const float* var   = (const float*)d_in[6];
    const float* w2    = (const float*)d_in[7];
    const float* b2    = (const float*)d_in[8];
    float* out = (float*)d_out;

    char* ws = (char*)d_ws;
    float*          w1tf = (float*)ws;                            // 16384 f = 64 KB
    float*          b1f  = (float*)(ws + 65536);                  // 64 f
    unsigned short* w2p  = (unsigned short*)(ws + 65792);         // 65536 bf16 = 128 KB
    unsigned short* ybf  = (unsigned short*)(ws + 196864);        // 2,097,152 bf16 = 4 MB

    prep1_kernel<<<64, 256, 0, stream>>>(w1, b1, gamma, beta, mean, var, w1tf, b1f);
    prep2_kernel<<<256, 256, 0, stream>>>(w2, w2p);
    conv1_kernel<<<dim3(2, HH, BB), 256, 0, stream>>>(x, w1tf, b1f, ybf);
    invol_kernel<<<dim3(HH, BB, 2), 256, 0, stream>>>(x, ybf, w2p, b2, out);
}

// Round 4
// 132.764 us; speedup vs baseline: 2.5055x; 1.4830x over previous
//
#include <hip/hip_runtime.h>

// Problem constants
#define BB   8
#define CC   256
#define HH   64
#define WW   64
#define CR   64     // reduced channels
#define NG   32     // groups
#define GC   8      // group_channels
#define KK   25     // 5x5 taps
#define HW   (HH*WW)

typedef __attribute__((ext_vector_type(8))) short short8;   // 8 bf16 = 4 VGPRs
typedef __attribute__((ext_vector_type(4))) float f32x4;    // MFMA C/D

__device__ __forceinline__ unsigned short f2bf(float f) {
    unsigned u = __builtin_bit_cast(unsigned, f);
    u += 0x7FFFu + ((u >> 16) & 1u);          // round-to-nearest-even
    return (unsigned short)(u >> 16);
}

// ---------------------------------------------------------------------------
// prep1: fold BN into w1, pack to bf16 A-fragment layout for 16x16x32 MFMA.
// A[m=r][k=c]: lane l holds r = mt*16 + (l&15), c = ki*32 + (l>>4)*8 + j.
// w1a[((ki*4+mt)*64 + l)*8 + j]. Also b1f (fp32 folded bias).
// ---------------------------------------------------------------------------
__global__ __launch_bounds__(256) void prep1_kernel(
    const float* __restrict__ w1, const float* __restrict__ b1,
    const float* __restrict__ gamma, const float* __restrict__ beta,
    const float* __restrict__ mean, const float* __restrict__ var,
    unsigned short* __restrict__ w1a, float* __restrict__ b1f)
{
    int idx = blockIdx.x * 256 + threadIdx.x;   // 0..16383
    int j  = idx & 7;
    int l  = (idx >> 3) & 63;
    int mt = (idx >> 9) & 3;
    int ki = (idx >> 11) & 7;
    int r  = mt * 16 + (l & 15);
    int c  = ki * 32 + (l >> 4) * 8 + j;
    float scale = gamma[r] * rsqrtf(var[r] + 1e-5f);
    w1a[idx] = f2bf(w1[r * CC + c] * scale);
    if (idx < CR) {
        float s = gamma[idx] * rsqrtf(var[idx] + 1e-5f);
        b1f[idx] = (b1[idx] - mean[idx]) * s + beta[idx];
    }
}

// ---------------------------------------------------------------------------
// prep2: pack w2 into bf16 B-fragment layout (unchanged from round 3).
// ---------------------------------------------------------------------------
__global__ __launch_bounds__(256) void prep2_kernel(
    const float* __restrict__ w2, unsigned short* __restrict__ w2p)
{
    int idx = blockIdx.x * 256 + threadIdx.x;   // 0..65535
    int j  = idx & 7;
    int l  = (idx >> 3) & 63;
    int ki = (idx >> 9) & 1;
    int nt = (idx >> 10) & 1;
    int g  = idx >> 11;
    int nl = nt * 16 + (l & 15);
    int k  = ki * 32 + (l >> 4) * 8 + j;
    float v = (nl < KK) ? w2[(g * KK + nl) * CR + k] : 0.0f;
    w2p[idx] = f2bf(v);
}

// ---------------------------------------------------------------------------
// conv1 (MFMA): y[px][r] = ReLU6(x[px][c] . w1a[r][c] + b1f[r]) -> bf16
// ybf[b][h][px][r]. Grid (H,B)=512 blocks, 4 waves; wave wv owns px tile
// wv*16..+16 (n = px), all 64 r (4 m-tiles). B-frag (x) via per-lane global
// loads: lane l reads 8 consecutive c at px=l&15 -- each instr covers 4 fully
// used 64B segments; every x byte read exactly once per block. A-frag (w1a)
// is a single coalesced b128 per (ki,mt). No LDS, no scalar loads in loop.
// ---------------------------------------------------------------------------
__global__ __launch_bounds__(256) void conv1_kernel(
    const float* __restrict__ x, const unsigned short* __restrict__ w1a,
    const float* __restrict__ b1f, unsigned short* __restrict__ ybf)
{
    const int tid  = threadIdx.x;
    const int h    = blockIdx.x;
    const int b    = blockIdx.y;
    const int lane = tid & 63;
    const int wv   = tid >> 6;
    const int l15  = lane & 15;
    const int q    = lane >> 4;
    const int px   = wv * 16 + l15;

    const float*  xc   = x + (size_t)b * CC * HW + h * WW + px;  // + c*HW
    const short8* w1a8 = (const short8*)w1a;

    f32x4 cfr[4];
    #pragma unroll
    for (int mt = 0; mt < 4; ++mt) cfr[mt] = (f32x4){0.f, 0.f, 0.f, 0.f};

    #pragma unroll
    for (int ki = 0; ki < 8; ++ki) {
        short8 bfr;
        #pragma unroll
        for (int j = 0; j < 8; ++j) {
            float v = xc[(ki * 32 + q * 8 + j) * HW];
            bfr[j] = (short)f2bf(v);
        }
        #pragma unroll
        for (int mt = 0; mt < 4; ++mt) {
            short8 afr = w1a8[(ki * 4 + mt) * 64 + lane];
            cfr[mt] = __builtin_amdgcn_mfma_f32_16x16x32_bf16(afr, bfr, cfr[mt], 0, 0, 0);
        }
    }

    // Epilogue: bias + ReLU6, pack bf16 pairs, store.
    // Lane holds col px=l15, rows r = mt*16 + q*4 + reg.
    unsigned short* yb = ybf + ((size_t)(b * HH + h) * WW + px) * CR;
    #pragma unroll
    for (int mt = 0; mt < 4; ++mt) {
        #pragma unroll
        for (int rp = 0; rp < 2; ++rp) {
            float v0 = cfr[mt][rp * 2 + 0] + b1f[mt * 16 + q * 4 + rp * 2 + 0];
            float v1 = cfr[mt][rp * 2 + 1] + b1f[mt * 16 + q * 4 + rp * 2 + 1];
            v0 = fminf(fmaxf(v0, 0.0f), 6.0f);
            v1 = fminf(fmaxf(v1, 0.0f), 6.0f);
            unsigned pk = (unsigned)f2bf(v0) | ((unsigned)f2bf(v1) << 16);
            *(unsigned*)(yb + mt * 16 + q * 4 + rp * 2) = pk;
        }
    }
}

// ---------------------------------------------------------------------------
// invol: per-pixel kernels via MFMA + involution accumulate (unchanged).
// ---------------------------------------------------------------------------
__global__ __launch_bounds__(256, 4) void invol_kernel(
    const float* __restrict__ x, const unsigned short* __restrict__ ybf,
    const unsigned short* __restrict__ w2p, const float* __restrict__ b2,
    float* __restrict__ out)
{
    __shared__ float klds[4][32 * 65];    // per-wave kern tiles, 33,280 B

    const int tid  = threadIdx.x;
    const int h    = blockIdx.x;
    const int b    = blockIdx.y;
    const int gq   = blockIdx.z;          // 0..1
    const int lane = tid & 63;
    const int wv   = __builtin_amdgcn_readfirstlane(tid >> 6);
    float* kw = klds[wv];

    const int l15 = lane & 15;
    const int q   = lane >> 4;

    // A fragments: y[px = mt*16+l15][k = ki*32 + q*8 + j]
    short8 afr[4][2];
    const unsigned short* yb = ybf + (size_t)(b * HH + h) * WW * CR;
    #pragma unroll
    for (int mt = 0; mt < 4; ++mt)
        #pragma unroll
        for (int ki = 0; ki < 2; ++ki)
            afr[mt][ki] = *(const short8*)(yb + (mt * 16 + l15) * CR + ki * 32 + q * 8);

    // hoisted clamped tap-column offsets
    int  wwc[5];
    bool val[5];
    #pragma unroll
    for (int dj = 0; dj < 5; ++dj) {
        int ww  = lane + dj - 2;
        val[dj] = (ww >= 0) && (ww < WW);
        wwc[dj] = min(max(ww, 0), WW - 1);
    }

    const short8* w2p8 = (const short8*)w2p;

    #pragma unroll 1
    for (int gl = 0; gl < 4; ++gl) {
        const int g = gq * 16 + wv * 4 + gl;   // uniform

        // C init = b2 broadcast (col n = nt*16 + l15)
        f32x4 cfr[4][2];
        #pragma unroll
        for (int nt = 0; nt < 2; ++nt) {
            int nl = nt * 16 + l15;
            float vb = b2[g * KK + min(nl, KK - 1)];
            vb = (nl < KK) ? vb : 0.0f;
            #pragma unroll
            for (int mt = 0; mt < 4; ++mt)
                cfr[mt][nt] = (f32x4){vb, vb, vb, vb};
        }

        // MFMA: kern[px][n] = sum_k y[px][k] * w2[n][k] + b2
        #pragma unroll
        for (int nt = 0; nt < 2; ++nt) {
            short8 bf0 = w2p8[((g * 2 + nt) * 2 + 0) * 64 + lane];
            short8 bf1 = w2p8[((g * 2 + nt) * 2 + 1) * 64 + lane];
            #pragma unroll
            for (int mt = 0; mt < 4; ++mt) {
                cfr[mt][nt] = __builtin_amdgcn_mfma_f32_16x16x32_bf16(
                    afr[mt][0], bf0, cfr[mt][nt], 0, 0, 0);
                cfr[mt][nt] = __builtin_amdgcn_mfma_f32_16x16x32_bf16(
                    afr[mt][1], bf1, cfr[mt][nt], 0, 0, 0);
            }
        }

        // C -> LDS: kern_lds[n][px], row stride 65
        #pragma unroll
        for (int mt = 0; mt < 4; ++mt)
            #pragma unroll
            for (int nt = 0; nt < 2; ++nt) {
                int n  = nt * 16 + l15;
                int px = mt * 16 + q * 4;
                #pragma unroll
                for (int r = 0; r < 4; ++r)
                    kw[n * 65 + px + r] = cfr[mt][nt][r];
            }

        // involution: out[ch][lane] += kern[t][lane] * x_tap
        float oacc[GC];
        #pragma unroll
        for (int j = 0; j < GC; ++j) oacc[j] = 0.0f;

        const float* xg = x + (size_t)(b * CC + g * GC) * HW;
        #pragma unroll
        for (int di = 0; di < 5; ++di) {
            int hh = h + di - 2;                 // uniform
            if (hh >= 0 && hh < HH) {
                float ks[5];
                #pragma unroll
                for (int dj = 0; dj < 5; ++dj) {
                    float kv = kw[(di * 5 + dj) * 65 + lane];   // 2-way, free
                    ks[dj] = val[dj] ? kv : 0.0f;
                }
                #pragma unroll
                for (int j = 0; j < GC; ++j) {
                    const float* xc2 = xg + (j * HH + hh) * WW;  // uniform base
                    #pragma unroll
                    for (int dj = 0; dj < 5; ++dj)
                        oacc[j] = fmaf(ks[dj], xc2[wwc[dj]], oacc[j]);
                }
            }
        }

        float* oc = out + ((size_t)(b * CC + g * GC) * HH + h) * WW + lane;
        #pragma unroll
        for (int j = 0; j < GC; ++j) oc[j * HW] = oacc[j];
    }
}

extern "C" void kernel_launch(void* const* d_in, const int* in_sizes, int n_in,
                              void* d_out, int out_size, void* d_ws, size_t ws_size,
                              hipStream_t stream) {
    const float* x     = (const float*)d_in[0];
    const float* w1    = (const float*)d_in[1];
    const float* b1    = (const float*)d_in[2];
    const float* gamma = (const float*)d_in[3];
    const float* beta  = (const float*)d_in[4];
    const float* mean  = (const float*)d_in[5];
    const float* var   = (const float*)d_in[6];
    const float* w2    = (const float*)d_in[7];
    const float* b2    = (const float*)d_in[8];
    float* out = (float*)d_out;

    char* ws = (char*)d_ws;
    unsigned short* w1a = (unsigned short*)ws;                    // 16384 bf16 = 32 KB
    float*          b1f = (float*)(ws + 32768);                   // 64 f = 256 B
    unsigned short* w2p = (unsigned short*)(ws + 33024);          // 65536 bf16 = 128 KB
    unsigned short* ybf = (unsigned short*)(ws + 164096);         // 2,097,152 bf16 = 4 MB

    prep1_kernel<<<64, 256, 0, stream>>>(w1, b1, gamma, beta, mean, var, w1a, b1f);
    prep2_kernel<<<256, 256, 0, stream>>>(w2, w2p);
    conv1_kernel<<<dim3(HH, BB), 256, 0, stream>>>(x, w1a, b1f, ybf);
    invol_kernel<<<dim3(HH, BB, 2), 256, 0, stream>>>(x, ybf, w2p, b2, out);
}